// Round 5
// baseline (183.090 us; speedup 1.0000x reference)
//
#include <hip/hip_runtime.h>
#include <stdint.h>

// B=4, S=2048, D=1024 self-attention, fp32 in/out.
// cvt(fp32->bf16, W^T) -> fused QKV GEMM -> scores GEMM (fp16 out, *1/32) ->
// softmax (fp16 in -> bf16 P) -> PV GEMM (fp32 out).
//
// r14: exact r11 config (best, 174.3us) for cvt/qkv/scores/softmax; pv is
// the single experiment: BN 128->64 (512 tiles, 20KB ring-3 slot -> 60KB
// LDS -> 2 blk/CU fully resident, zero tail). pv's co-scheduling now comes
// from independent blocks (qkv's proven mechanism), not more lockstep waves
// (r13's failure). Same core schedule, LA=4 LB=1 L=5.
// Ledger: r10 regress (2-phase graft), r11 best (4-phase scores, neutral),
// r12 regress (128^2: FETCH 2x), r13 regress (512-thr pv lockstep).
// Workspace: [0,16M) X16 | [16,22M) TQ/TK/TV | [22,38M) Q16 | [38,54M) K16 |
//            [54,70M) VT [B][D][S] | [70,102M) SC16 fp16 | P16 aliases Q16+K16.

typedef __attribute__((ext_vector_type(8))) short bf16x8;
typedef __attribute__((ext_vector_type(4))) float f32x4;
typedef __attribute__((ext_vector_type(4))) unsigned short u16x4;
typedef __attribute__((ext_vector_type(8))) unsigned short u16x8;

__device__ __forceinline__ unsigned short f2bf(float f) {
  union { float f; unsigned u; } v; v.f = f;
  return (unsigned short)((v.u + 0x7FFFu + ((v.u >> 16) & 1u)) >> 16);
}
__device__ __forceinline__ unsigned short f2h(float f) {
  union { _Float16 h; unsigned short u; } v; v.h = (_Float16)f;
  return v.u;
}
__device__ __forceinline__ float h2f(unsigned short u) {
  union { unsigned short u; _Float16 h; } v; v.u = u;
  return (float)v.h;
}

__device__ __forceinline__ void gload16(const void* g, void* l) {
  __builtin_amdgcn_global_load_lds(
      (const __attribute__((address_space(1))) unsigned int*)g,
      (__attribute__((address_space(3))) unsigned int*)l, 16, 0, 0);
}

template <int N>
__device__ __forceinline__ void wait_vm() {
  asm volatile("s_waitcnt vmcnt(%0)" ::"n"(N) : "memory");
}

__device__ __forceinline__ int swz8(int bid, int cpx) {
  return (bid & 7) * cpx + (bid >> 3);  // bijective when nwg%8==0
}

__device__ __forceinline__ f32x4 mfma16(bf16x8 a, bf16x8 b, f32x4 c) {
  return __builtin_amdgcn_mfma_f32_16x16x32_bf16(a, b, c, 0, 0, 0);
}

// ================= r6-proven core: 256 thr, BM256 x BN128, ring-3 ==========
__device__ __forceinline__ void gemm_core(
    const unsigned short* __restrict__ A, const unsigned short* __restrict__ Bt,
    const int lda, const int ldb, const int nt,
    const long aRow0, const long bRow0, char* lds,
    f32x4 (&acc)[8][4]) {
  constexpr int A_BYTES = 256 * 64;           // 16KB
  constexpr int SLOT = A_BYTES + 128 * 64;    // 24KB
  constexpr int LA = 4, LB = 2, L = LA + LB;  // 16B gloads per thread per tile
  const int tid = threadIdx.x;
  const int lane = tid & 63;
  const int wid = tid >> 6;
  const int wm = wid >> 1, wn = wid & 1;
  const int l15 = lane & 15, lhi = lane >> 4;

  long goffA[LA]; int ldsoffA[LA];
#pragma unroll
  for (int j = 0; j < LA; ++j) {
    const int local = j * 4096 + tid * 16;
    const int row = local >> 6, ch = (local >> 4) & 3;
    goffA[j] = (aRow0 + row) * (long)lda + ((ch ^ ((row >> 1) & 3)) << 3);
    ldsoffA[j] = local;
  }
  long goffB[LB]; int ldsoffB[LB];
#pragma unroll
  for (int j = 0; j < LB; ++j) {
    const int local = j * 4096 + tid * 16;
    const int row = local >> 6, ch = (local >> 4) & 3;
    goffB[j] = (bRow0 + row) * (long)ldb + ((ch ^ ((row >> 1) & 3)) << 3);
    ldsoffB[j] = A_BYTES + local;
  }
  int raddrA[8];
#pragma unroll
  for (int m = 0; m < 8; ++m) {
    const int row = wm * 128 + m * 16 + l15;
    raddrA[m] = row * 64 + ((lhi ^ ((row >> 1) & 3)) << 4);
  }
  int raddrB[4];
#pragma unroll
  for (int n = 0; n < 4; ++n) {
    const int row = wn * 64 + n * 16 + l15;
    raddrB[n] = A_BYTES + row * 64 + ((lhi ^ ((row >> 1) & 3)) << 4);
  }

  const f32x4 z4 = {0.f, 0.f, 0.f, 0.f};
#pragma unroll
  for (int m = 0; m < 8; ++m)
#pragma unroll
    for (int n = 0; n < 4; ++n) acc[m][n] = z4;

  auto stage_tile = [&](int T) {
    char* dst = lds + (T % 3) * SLOT;
    const int k0 = T << 5;
#pragma unroll
    for (int j = 0; j < LA; ++j) gload16(A + goffA[j] + k0, dst + ldsoffA[j]);
#pragma unroll
    for (int j = 0; j < LB; ++j) gload16(Bt + goffB[j] + k0, dst + ldsoffB[j]);
  };

  stage_tile(0);
  stage_tile(1);
  wait_vm<L>();
  __builtin_amdgcn_s_barrier();

  for (int t = 0; t < nt; ++t) {
    const char* sb = lds + (t % 3) * SLOT;
    bf16x8 af[8], bfr[4];
#pragma unroll
    for (int n = 0; n < 4; ++n) bfr[n] = *(const bf16x8*)(sb + raddrB[n]);
#pragma unroll
    for (int m = 0; m < 8; ++m) af[m] = *(const bf16x8*)(sb + raddrA[m]);
    if (t + 2 < nt) stage_tile(t + 2);
    __builtin_amdgcn_s_setprio(1);
#pragma unroll
    for (int m = 0; m < 8; ++m)
#pragma unroll
      for (int n = 0; n < 4; ++n) acc[m][n] = mfma16(af[m], bfr[n], acc[m][n]);
    __builtin_amdgcn_s_setprio(0);
    if (t + 2 < nt) wait_vm<L>();
    else if (t + 1 < nt) wait_vm<0>();
    __builtin_amdgcn_s_barrier();
  }
}

// ===== pv core: 256 thr, BM256 x BN64, ring-3 (20KB slot, 60KB total) ======
// Same schedule as gemm_core; LA=4, LB=1, L=5.  4 waves 2Mx2N, wave tile
// 128x32 (MF=8, NF=2).  512 tiles -> 2 blk/CU fully resident, zero tail.
__device__ __forceinline__ void gemm_core_pv(
    const unsigned short* __restrict__ A, const unsigned short* __restrict__ Bt,
    const int lda, const int ldb, const int nt,
    const long aRow0, const long bRow0, char* lds,
    f32x4 (&acc)[8][2]) {
  constexpr int A_BYTES = 256 * 64;           // 16KB
  constexpr int SLOT = A_BYTES + 64 * 64;     // 20KB
  constexpr int LA = 4, LB = 1, L = LA + LB;  // 16B gloads per thread per tile
  const int tid = threadIdx.x;
  const int lane = tid & 63;
  const int wid = tid >> 6;
  const int wm = wid >> 1, wn = wid & 1;
  const int l15 = lane & 15, lhi = lane >> 4;

  long goffA[LA]; int ldsoffA[LA];
#pragma unroll
  for (int j = 0; j < LA; ++j) {
    const int local = j * 4096 + tid * 16;
    const int row = local >> 6, ch = (local >> 4) & 3;
    goffA[j] = (aRow0 + row) * (long)lda + ((ch ^ ((row >> 1) & 3)) << 3);
    ldsoffA[j] = local;
  }
  long goffB; int ldsoffB;
  {
    const int local = tid * 16;  // 256 thr x 16B = 4KB = full 64x32 B tile
    const int row = local >> 6, ch = (local >> 4) & 3;
    goffB = (bRow0 + row) * (long)ldb + ((ch ^ ((row >> 1) & 3)) << 3);
    ldsoffB = A_BYTES + local;
  }
  int raddrA[8];
#pragma unroll
  for (int m = 0; m < 8; ++m) {
    const int row = wm * 128 + m * 16 + l15;
    raddrA[m] = row * 64 + ((lhi ^ ((row >> 1) & 3)) << 4);
  }
  int raddrB[2];
#pragma unroll
  for (int n = 0; n < 2; ++n) {
    const int row = wn * 32 + n * 16 + l15;
    raddrB[n] = A_BYTES + row * 64 + ((lhi ^ ((row >> 1) & 3)) << 4);
  }

  const f32x4 z4 = {0.f, 0.f, 0.f, 0.f};
#pragma unroll
  for (int m = 0; m < 8; ++m)
#pragma unroll
    for (int n = 0; n < 2; ++n) acc[m][n] = z4;

  auto stage_tile = [&](int T) {
    char* dst = lds + (T % 3) * SLOT;
    const int k0 = T << 5;
#pragma unroll
    for (int j = 0; j < LA; ++j) gload16(A + goffA[j] + k0, dst + ldsoffA[j]);
    gload16(Bt + goffB + k0, dst + ldsoffB);
  };

  stage_tile(0);
  stage_tile(1);
  wait_vm<L>();  // tile 0 landed; tile 1's 5 loads in flight
  __builtin_amdgcn_s_barrier();

  for (int t = 0; t < nt; ++t) {
    const char* sb = lds + (t % 3) * SLOT;
    bf16x8 af[8], bfr[2];
#pragma unroll
    for (int n = 0; n < 2; ++n) bfr[n] = *(const bf16x8*)(sb + raddrB[n]);
#pragma unroll
    for (int m = 0; m < 8; ++m) af[m] = *(const bf16x8*)(sb + raddrA[m]);
    if (t + 2 < nt) stage_tile(t + 2);
    __builtin_amdgcn_s_setprio(1);
#pragma unroll
    for (int m = 0; m < 8; ++m)
#pragma unroll
      for (int n = 0; n < 2; ++n) acc[m][n] = mfma16(af[m], bfr[n], acc[m][n]);
    __builtin_amdgcn_s_setprio(0);
    if (t + 2 < nt) wait_vm<L>();   // retire t+1's 5, keep t+2's 5 in flight
    else if (t + 1 < nt) wait_vm<0>();
    __builtin_amdgcn_s_barrier();
  }
}

// ====== r11 scores core: 512 thr, BM=BN=256, BK=64, double-buffer ==========
__device__ __forceinline__ void gemm_core3(
    const unsigned short* __restrict__ A, const unsigned short* __restrict__ Bt,
    const int lda, const int ldb, const int nt64,
    const long aRow0, const long bRow0, char* lds,
    f32x4 (&acc)[8][4]) {
  constexpr int SLICE = 256 * 64;     // 16KB
  constexpr int A_BYTES = 2 * SLICE;  // 32KB
  constexpr int SLOT = 2 * A_BYTES;   // 64KB
  const int tid = threadIdx.x;
  const int lane = tid & 63;
  const int wid = tid >> 6;
  const int wm = wid >> 2, wn = wid & 3;
  const int l15 = lane & 15, lhi = lane >> 4;

  long goffA[2][2], goffB[2][2];  // [kk][j]
  int ldsoff[2];
#pragma unroll
  for (int j = 0; j < 2; ++j) {
    const int local = j * 8192 + tid * 16;
    const int row = local >> 6, ch = (local >> 4) & 3;
    ldsoff[j] = local;
    const int kalt = (ch ^ ((row >> 1) & 3)) << 3;
#pragma unroll
    for (int kk = 0; kk < 2; ++kk) {
      goffA[kk][j] = (aRow0 + row) * (long)lda + kk * 32 + kalt;
      goffB[kk][j] = (bRow0 + row) * (long)ldb + kk * 32 + kalt;
    }
  }
  int raddrA[8];
#pragma unroll
  for (int m = 0; m < 8; ++m) {
    const int row = wm * 128 + m * 16 + l15;
    raddrA[m] = row * 64 + ((lhi ^ ((row >> 1) & 3)) << 4);
  }
  int raddrB[4];
#pragma unroll
  for (int n = 0; n < 4; ++n) {
    const int row = wn * 64 + n * 16 + l15;
    raddrB[n] = row * 64 + ((lhi ^ ((row >> 1) & 3)) << 4);
  }

  const f32x4 z4 = {0.f, 0.f, 0.f, 0.f};
#pragma unroll
  for (int m = 0; m < 8; ++m)
#pragma unroll
    for (int n = 0; n < 4; ++n) acc[m][n] = z4;

  auto stageA = [&](int s, int kk, int T) {
    char* dst = lds + s * SLOT + kk * SLICE;
    const long k0 = (long)T << 6;
#pragma unroll
    for (int j = 0; j < 2; ++j) gload16(A + goffA[kk][j] + k0, dst + ldsoff[j]);
  };
  auto stageB = [&](int s, int kk, int T) {
    char* dst = lds + s * SLOT + A_BYTES + kk * SLICE;
    const long k0 = (long)T << 6;
#pragma unroll
    for (int j = 0; j < 2; ++j) gload16(Bt + goffB[kk][j] + k0, dst + ldsoff[j]);
  };

  stageA(0, 0, 0); stageB(0, 0, 0);
  stageA(0, 1, 0); stageB(0, 1, 0);
  wait_vm<4>();
  __builtin_amdgcn_s_barrier();

  int cur = 0;
  for (int t = 0; t < nt64; ++t) {
    const char* sb = lds + cur * SLOT;
    const int nxt = cur ^ 1;
    const bool pf = (t + 1 < nt64);
    bf16x8 a0[4], a1[4], b0[4], b1[4];
    // ---- P1
#pragma unroll
    for (int n = 0; n < 4; ++n) b0[n] = *(const bf16x8*)(sb + A_BYTES + raddrB[n]);
#pragma unroll
    for (int m = 0; m < 4; ++m) a0[m] = *(const bf16x8*)(sb + raddrA[m]);
    if (pf) stageA(nxt, 0, t + 1);
    __builtin_amdgcn_s_barrier();
    __builtin_amdgcn_s_setprio(1);
#pragma unroll
    for (int m = 0; m < 4; ++m)
#pragma unroll
      for (int n = 0; n < 4; ++n) acc[m][n] = mfma16(a0[m], b0[n], acc[m][n]);
    __builtin_amdgcn_s_setprio(0);
    __builtin_amdgcn_s_barrier();
    // ---- P2
#pragma unroll
    for (int m = 0; m < 4; ++m) a1[m] = *(const bf16x8*)(sb + raddrA[4 + m]);
    if (pf) { stageB(nxt, 0, t + 1); wait_vm<4>(); }
    else wait_vm<0>();
    __builtin_amdgcn_s_barrier();
    __builtin_amdgcn_s_setprio(1);
#pragma unroll
    for (int m = 0; m < 4; ++m)
#pragma unroll
      for (int n = 0; n < 4; ++n)
        acc[4 + m][n] = mfma16(a1[m], b0[n], acc[4 + m][n]);
    __builtin_amdgcn_s_setprio(0);
    __builtin_amdgcn_s_barrier();
    // ---- P3
#pragma unroll
    for (int n = 0; n < 4; ++n)
      b1[n] = *(const bf16x8*)(sb + A_BYTES + SLICE + raddrB[n]);
#pragma unroll
    for (int m = 0; m < 4; ++m) a0[m] = *(const bf16x8*)(sb + SLICE + raddrA[m]);
    if (pf) stageA(nxt, 1, t + 1);
    __builtin_amdgcn_s_barrier();
    __builtin_amdgcn_s_setprio(1);
#pragma unroll
    for (int m = 0; m < 4; ++m)
#pragma unroll
      for (int n = 0; n < 4; ++n) acc[m][n] = mfma16(a0[m], b1[n], acc[m][n]);
    __builtin_amdgcn_s_setprio(0);
    __builtin_amdgcn_s_barrier();
    // ---- P4
#pragma unroll
    for (int m = 0; m < 4; ++m)
      a1[m] = *(const bf16x8*)(sb + SLICE + raddrA[4 + m]);
    if (pf) { stageB(nxt, 1, t + 1); wait_vm<4>(); }
    __builtin_amdgcn_s_barrier();
    __builtin_amdgcn_s_setprio(1);
#pragma unroll
    for (int m = 0; m < 4; ++m)
#pragma unroll
      for (int n = 0; n < 4; ++n)
        acc[4 + m][n] = mfma16(a1[m], b1[n], acc[4 + m][n]);
    __builtin_amdgcn_s_setprio(0);
    __builtin_amdgcn_s_barrier();
    cur = nxt;
  }
}

// ---- fused QKV: X[8192,1024] x {Wq,Wk,Wv}^T. BM256xBN128, grid 768. ----
__global__ __launch_bounds__(256, 2) void qkv_kernel(
    const unsigned short* __restrict__ X, const unsigned short* __restrict__ TQ,
    const unsigned short* __restrict__ TK, const unsigned short* __restrict__ TV,
    const float* __restrict__ bq, const float* __restrict__ bk,
    const float* __restrict__ bv, unsigned short* __restrict__ Q16,
    unsigned short* __restrict__ K16, unsigned short* __restrict__ VT) {
  __shared__ char lds[3 * 24576];
  const int wgid = swz8(blockIdx.x, 96);
  const int tm = wgid / 24, tn = wgid % 24;
  const int w = tn >> 3, c = tn & 7;
  const unsigned short* Bt = w == 0 ? TQ : (w == 1 ? TK : TV);
  const float* bias = w == 0 ? bq : (w == 1 ? bk : bv);

  f32x4 acc[8][4];
  gemm_core(X, Bt, 1024, 1024, 32, (long)tm * 256, (long)c * 128, lds, acc);

  const int tid = threadIdx.x, lane = tid & 63, wid = tid >> 6;
  const int wm = wid >> 1, wn = wid & 1;
  const int l15 = lane & 15, lhi = lane >> 4;
  const int rowBase = tm * 256 + wm * 128;
  const int colBase = c * 128 + wn * 64;  // within-weight column (D index)
  if (w < 2) {
    unsigned short* C = w == 0 ? Q16 : K16;
#pragma unroll
    for (int m = 0; m < 8; ++m)
#pragma unroll
      for (int n = 0; n < 4; ++n) {
        const int col = colBase + n * 16 + l15;
        const float bvv = bias[col];
#pragma unroll
        for (int j = 0; j < 4; ++j) {
          const int row = rowBase + m * 16 + lhi * 4 + j;
          C[(long)row * 1024 + col] = f2bf(acc[m][n][j] + bvv);
        }
      }
  } else {
#pragma unroll
    for (int m = 0; m < 8; ++m)
#pragma unroll
      for (int n = 0; n < 4; ++n) {
        const int col = colBase + n * 16 + l15;
        const float bvv = bias[col];
        const int row0 = rowBase + m * 16 + lhi * 4;
        const int b = row0 >> 11, s = row0 & 2047;
        u16x4 v;
#pragma unroll
        for (int j = 0; j < 4; ++j) v[j] = f2bf(acc[m][n][j] + bvv);
        *reinterpret_cast<u16x4*>(&VT[(long)b * 2097152 + (long)col * 2048 + s]) = v;
      }
  }
}

// ---- scores = Q K^T / 32 per batch, fp16 out. BM256xBN256 BK64, grid 256.
__global__ __launch_bounds__(512, 1) void scores_kernel(
    const unsigned short* __restrict__ Q16, const unsigned short* __restrict__ K16,
    unsigned short* __restrict__ SC16) {
  extern __shared__ char lds[];  // 131072 bytes
  const int wgid = swz8(blockIdx.x, 32);
  const int bz = wgid >> 6, tm = (wgid >> 3) & 7, tn = wgid & 7;
  const unsigned short* A = Q16 + (long)bz * 2097152;
  const unsigned short* Bt = K16 + (long)bz * 2097152;

  f32x4 acc[8][4];
  gemm_core3(A, Bt, 1024, 1024, 16, (long)tm * 256, (long)tn * 256, lds, acc);

  unsigned short* C = SC16 + (long)bz * 4194304;
  const int tid = threadIdx.x, lane = tid & 63, wid = tid >> 6;
  const int wm = wid >> 2, wn = wid & 3;
  const int l15 = lane & 15, lhi = lane >> 4;
  const int rowBase = tm * 256 + wm * 128;
  const int colBase = tn * 256 + wn * 64;
#pragma unroll
  for (int m = 0; m < 8; ++m)
#pragma unroll
    for (int n = 0; n < 4; ++n) {
      const int col = colBase + n * 16 + l15;
#pragma unroll
      for (int j = 0; j < 4; ++j) {
        const int row = rowBase + m * 16 + lhi * 4 + j;
        C[(long)row * 2048 + col] = f2h(acc[m][n][j] * (1.f / 32.f));
      }
    }
}

// ---- out = P V per batch (Bt = VT[D][S]). BM256xBN64, grid 512. ----
__global__ __launch_bounds__(256, 2) void pv_kernel(
    const unsigned short* __restrict__ P16, const unsigned short* __restrict__ VT,
    float* __restrict__ out) {
  __shared__ char lds[3 * 20480];
  const int wgid = swz8(blockIdx.x, 64);
  const int bz = wgid >> 7, tm = (wgid >> 4) & 7, tn = wgid & 15;
  const unsigned short* A = P16 + (long)bz * 4194304;
  const unsigned short* Bt = VT + (long)bz * 2097152;

  f32x4 acc[8][2];
  gemm_core_pv(A, Bt, 2048, 2048, 64, (long)tm * 256, (long)tn * 64, lds, acc);

  float* C = out + (long)bz * 2097152;
  const int tid = threadIdx.x, lane = tid & 63, wid = tid >> 6;
  const int wm = wid >> 1, wn = wid & 1;
  const int l15 = lane & 15, lhi = lane >> 4;
  const int rowBase = tm * 256 + wm * 128;
  const int colBase = tn * 64 + wn * 32;
#pragma unroll
  for (int m = 0; m < 8; ++m)
#pragma unroll
    for (int n = 0; n < 2; ++n) {
      const int col = colBase + n * 16 + l15;
#pragma unroll
      for (int j = 0; j < 4; ++j) {
        const int row = rowBase + m * 16 + lhi * 4 + j;
        C[(long)row * 1024 + col] = acc[m][n][j];
      }
    }
}

// ---- fp32 -> bf16, 4 elems/thread ----
__global__ __launch_bounds__(256) void cvt4(const float* __restrict__ in,
                                            unsigned short* __restrict__ out) {
  int i = blockIdx.x * 256 + threadIdx.x;
  float4 v = reinterpret_cast<const float4*>(in)[i];
  u16x4 r;
  r[0] = f2bf(v.x); r[1] = f2bf(v.y); r[2] = f2bf(v.z); r[3] = f2bf(v.w);
  reinterpret_cast<u16x4*>(out)[i] = r;
}

// ---- W [K,N] fp32 -> Wt [N,K] bf16 ----
__global__ __launch_bounds__(256) void cvtWt(
    const float* __restrict__ w0, const float* __restrict__ w1, const float* __restrict__ w2,
    unsigned short* __restrict__ t0, unsigned short* __restrict__ t1, unsigned short* __restrict__ t2) {
  const float* w = blockIdx.y == 0 ? w0 : (blockIdx.y == 1 ? w1 : w2);
  unsigned short* t = blockIdx.y == 0 ? t0 : (blockIdx.y == 1 ? t1 : t2);
  int id = blockIdx.x * 256 + threadIdx.x;
  int k = id >> 10, n = id & 1023;
  t[n * 1024 + k] = f2bf(w[id]);
}

// ---- row softmax: fp16 scores -> bf16 P.  One block per row (8 elems/thr).
__global__ __launch_bounds__(256) void softmax_rows(const unsigned short* __restrict__ S,
                                                    unsigned short* __restrict__ P) {
  const long row = blockIdx.x;
  const u16x8* src = reinterpret_cast<const u16x8*>(S + row * 2048);
  const int tid = threadIdx.x;
  u16x8 a = src[tid];
  float v[8];
#pragma unroll
  for (int i = 0; i < 8; ++i) v[i] = h2f(a[i]);
  float m = v[0];
#pragma unroll
  for (int i = 1; i < 8; ++i) m = fmaxf(m, v[i]);
#pragma unroll
  for (int o = 32; o > 0; o >>= 1) m = fmaxf(m, __shfl_xor(m, o));
  __shared__ float red[8];
  const int wid = tid >> 6, lane = tid & 63;
  if (lane == 0) red[wid] = m;
  __syncthreads();
  m = fmaxf(fmaxf(red[0], red[1]), fmaxf(red[2], red[3]));
  float s = 0.f;
#pragma unroll
  for (int i = 0; i < 8; ++i) { v[i] = __expf(v[i] - m); s += v[i]; }
#pragma unroll
  for (int o = 32; o > 0; o >>= 1) s += __shfl_xor(s, o);
  if (lane == 0) red[4 + wid] = s;
  __syncthreads();
  s = (red[4] + red[5]) + (red[6] + red[7]);
  const float inv = 1.f / s;
  u16x8 p;
#pragma unroll
  for (int i = 0; i < 8; ++i) p[i] = f2bf(v[i] * inv);
  reinterpret_cast<u16x8*>(P + row * 2048)[tid] = p;
}

extern "C" void kernel_launch(void* const* d_in, const int* in_sizes, int n_in,
                              void* d_out, int out_size, void* d_ws, size_t ws_size,
                              hipStream_t stream) {
  const float* x  = (const float*)d_in[0];
  const float* Wq = (const float*)d_in[1];
  const float* bq = (const float*)d_in[2];
  const float* Wk = (const float*)d_in[3];
  const float* bk = (const float*)d_in[4];
  const float* Wv = (const float*)d_in[5];
  const float* bv = (const float*)d_in[6];
  float* out = (float*)d_out;

  char* ws = (char*)d_ws;
  const size_t MB = 1024 * 1024;
  unsigned short* X16 = (unsigned short*)(ws);
  unsigned short* TQ  = (unsigned short*)(ws + 16 * MB);
  unsigned short* TK  = (unsigned short*)(ws + 18 * MB);
  unsigned short* TV  = (unsigned short*)(ws + 20 * MB);
  unsigned short* Q16 = (unsigned short*)(ws + 22 * MB);
  unsigned short* K16 = (unsigned short*)(ws + 38 * MB);
  unsigned short* VT  = (unsigned short*)(ws + 54 * MB);
  unsigned short* SC16 = (unsigned short*)(ws + 70 * MB);
  unsigned short* P16 = Q16;  // alias Q16+K16 (32MB), dead after scores GEMM

  // allow 128KB dynamic LDS for scores_kernel (host-side attr, not captured)
  static bool attr_set = false;
  if (!attr_set) {
    hipFuncSetAttribute(reinterpret_cast<const void*>(scores_kernel),
                        hipFuncAttributeMaxDynamicSharedMemorySize, 131072);
    attr_set = true;
  }

  cvt4<<<8192, 256, 0, stream>>>(x, X16);
  cvtWt<<<dim3(4096, 3), 256, 0, stream>>>(Wq, Wk, Wv, TQ, TK, TV);

  qkv_kernel<<<768, 256, 0, stream>>>(X16, TQ, TK, TV, bq, bk, bv, Q16, K16, VT);
  scores_kernel<<<256, 512, 131072, stream>>>(Q16, K16, SC16);
  softmax_rows<<<4 * 2048, 256, 0, stream>>>(SC16, P16);
  pv_kernel<<<512, 256, 0, stream>>>(P16, VT, out);

  (void)in_sizes; (void)n_in; (void)out_size; (void)ws_size;
}

// Round 6
// 182.079 us; speedup vs baseline: 1.0056x; 1.0056x over previous
//
#include <hip/hip_runtime.h>
#include <stdint.h>

// B=4, S=2048, D=1024 self-attention, fp32 in/out.
// cvt(fp32->bf16, W^T) -> fused QKV GEMM -> scores GEMM (fp16 out, *1/32) ->
// softmax (fp16 in -> bf16 P) -> PV GEMM (fp32 out).
//
// r15 (consolidation): exact r11 configuration -- the session best (174.3us)
// -- plus the cvt4+cvtWt merge (single launch; mechanism independent of the
// failed experiments).  Ledger: r10 regress (2-phase graft), r11 BEST
// (4-phase scores, neutral vs r6 core), r12 regress (128^2 tiles: FETCH 2x,
// 16 MFMA/barrier), r13 regress (512-thr lockstep pv), r14 regress (BN=64
// pv, 16 MFMA/barrier).  Rule extracted: keep >=32 MFMA per wave per
// barrier-pair; co-scheduling must come from independent blocks.
//   qkv:    256-thr BM256xBN128 r6-core, grid 768, 2 blk/CU   (~832 TF)
//   scores: 512-thr BM=BN=256 BK64 4-phase dbuf, grid 256     (~840 TF)
//   pv:     256-thr BM256xBN128 r6-core, grid 256, 1 blk/CU   (~782 TF)
// Workspace: [0,16M) X16 | [16,22M) TQ/TK/TV | [22,38M) Q16 | [38,54M) K16 |
//            [54,70M) VT [B][D][S] | [70,102M) SC16 fp16 | P16 aliases Q16+K16.

typedef __attribute__((ext_vector_type(8))) short bf16x8;
typedef __attribute__((ext_vector_type(4))) float f32x4;
typedef __attribute__((ext_vector_type(4))) unsigned short u16x4;
typedef __attribute__((ext_vector_type(8))) unsigned short u16x8;

__device__ __forceinline__ unsigned short f2bf(float f) {
  union { float f; unsigned u; } v; v.f = f;
  return (unsigned short)((v.u + 0x7FFFu + ((v.u >> 16) & 1u)) >> 16);
}
__device__ __forceinline__ unsigned short f2h(float f) {
  union { _Float16 h; unsigned short u; } v; v.h = (_Float16)f;
  return v.u;
}
__device__ __forceinline__ float h2f(unsigned short u) {
  union { unsigned short u; _Float16 h; } v; v.u = u;
  return (float)v.h;
}

__device__ __forceinline__ void gload16(const void* g, void* l) {
  __builtin_amdgcn_global_load_lds(
      (const __attribute__((address_space(1))) unsigned int*)g,
      (__attribute__((address_space(3))) unsigned int*)l, 16, 0, 0);
}

template <int N>
__device__ __forceinline__ void wait_vm() {
  asm volatile("s_waitcnt vmcnt(%0)" ::"n"(N) : "memory");
}

__device__ __forceinline__ int swz8(int bid, int cpx) {
  return (bid & 7) * cpx + (bid >> 3);  // bijective when nwg%8==0
}

__device__ __forceinline__ f32x4 mfma16(bf16x8 a, bf16x8 b, f32x4 c) {
  return __builtin_amdgcn_mfma_f32_16x16x32_bf16(a, b, c, 0, 0, 0);
}

// ================= r6-proven core: 256 thr, BM256 x BN128, ring-3 ==========
__device__ __forceinline__ void gemm_core(
    const unsigned short* __restrict__ A, const unsigned short* __restrict__ Bt,
    const int lda, const int ldb, const int nt,
    const long aRow0, const long bRow0, char* lds,
    f32x4 (&acc)[8][4]) {
  constexpr int A_BYTES = 256 * 64;           // 16KB
  constexpr int SLOT = A_BYTES + 128 * 64;    // 24KB
  constexpr int LA = 4, LB = 2, L = LA + LB;  // 16B gloads per thread per tile
  const int tid = threadIdx.x;
  const int lane = tid & 63;
  const int wid = tid >> 6;
  const int wm = wid >> 1, wn = wid & 1;
  const int l15 = lane & 15, lhi = lane >> 4;

  long goffA[LA]; int ldsoffA[LA];
#pragma unroll
  for (int j = 0; j < LA; ++j) {
    const int local = j * 4096 + tid * 16;
    const int row = local >> 6, ch = (local >> 4) & 3;
    goffA[j] = (aRow0 + row) * (long)lda + ((ch ^ ((row >> 1) & 3)) << 3);
    ldsoffA[j] = local;
  }
  long goffB[LB]; int ldsoffB[LB];
#pragma unroll
  for (int j = 0; j < LB; ++j) {
    const int local = j * 4096 + tid * 16;
    const int row = local >> 6, ch = (local >> 4) & 3;
    goffB[j] = (bRow0 + row) * (long)ldb + ((ch ^ ((row >> 1) & 3)) << 3);
    ldsoffB[j] = A_BYTES + local;
  }
  int raddrA[8];
#pragma unroll
  for (int m = 0; m < 8; ++m) {
    const int row = wm * 128 + m * 16 + l15;
    raddrA[m] = row * 64 + ((lhi ^ ((row >> 1) & 3)) << 4);
  }
  int raddrB[4];
#pragma unroll
  for (int n = 0; n < 4; ++n) {
    const int row = wn * 64 + n * 16 + l15;
    raddrB[n] = A_BYTES + row * 64 + ((lhi ^ ((row >> 1) & 3)) << 4);
  }

  const f32x4 z4 = {0.f, 0.f, 0.f, 0.f};
#pragma unroll
  for (int m = 0; m < 8; ++m)
#pragma unroll
    for (int n = 0; n < 4; ++n) acc[m][n] = z4;

  auto stage_tile = [&](int T) {
    char* dst = lds + (T % 3) * SLOT;
    const int k0 = T << 5;
#pragma unroll
    for (int j = 0; j < LA; ++j) gload16(A + goffA[j] + k0, dst + ldsoffA[j]);
#pragma unroll
    for (int j = 0; j < LB; ++j) gload16(Bt + goffB[j] + k0, dst + ldsoffB[j]);
  };

  stage_tile(0);
  stage_tile(1);
  wait_vm<L>();
  __builtin_amdgcn_s_barrier();

  for (int t = 0; t < nt; ++t) {
    const char* sb = lds + (t % 3) * SLOT;
    bf16x8 af[8], bfr[4];
#pragma unroll
    for (int n = 0; n < 4; ++n) bfr[n] = *(const bf16x8*)(sb + raddrB[n]);
#pragma unroll
    for (int m = 0; m < 8; ++m) af[m] = *(const bf16x8*)(sb + raddrA[m]);
    if (t + 2 < nt) stage_tile(t + 2);
    __builtin_amdgcn_s_setprio(1);
#pragma unroll
    for (int m = 0; m < 8; ++m)
#pragma unroll
      for (int n = 0; n < 4; ++n) acc[m][n] = mfma16(af[m], bfr[n], acc[m][n]);
    __builtin_amdgcn_s_setprio(0);
    if (t + 2 < nt) wait_vm<L>();
    else if (t + 1 < nt) wait_vm<0>();
    __builtin_amdgcn_s_barrier();
  }
}

// ====== r11 scores core: 512 thr, BM=BN=256, BK=64, double-buffer ==========
// 4 phases x 16 MFMA per K-tile; counted vmcnt(4) twice per tile (never 0
// mid-loop).  Wait algebra: end P2 outstanding {A1,B1(t),A0,B0(t+1)}=8 ->
// vmcnt(4) retires A1,B1(t) for P3/P4; end P4 outstanding {t+1's 8} ->
// vmcnt(4) retires A0,B0(t+1) for next-iter P1/P2.
__device__ __forceinline__ void gemm_core3(
    const unsigned short* __restrict__ A, const unsigned short* __restrict__ Bt,
    const int lda, const int ldb, const int nt64,
    const long aRow0, const long bRow0, char* lds,
    f32x4 (&acc)[8][4]) {
  constexpr int SLICE = 256 * 64;     // 16KB
  constexpr int A_BYTES = 2 * SLICE;  // 32KB
  constexpr int SLOT = 2 * A_BYTES;   // 64KB
  const int tid = threadIdx.x;
  const int lane = tid & 63;
  const int wid = tid >> 6;
  const int wm = wid >> 2, wn = wid & 3;
  const int l15 = lane & 15, lhi = lane >> 4;

  long goffA[2][2], goffB[2][2];  // [kk][j]
  int ldsoff[2];
#pragma unroll
  for (int j = 0; j < 2; ++j) {
    const int local = j * 8192 + tid * 16;
    const int row = local >> 6, ch = (local >> 4) & 3;
    ldsoff[j] = local;
    const int kalt = (ch ^ ((row >> 1) & 3)) << 3;
#pragma unroll
    for (int kk = 0; kk < 2; ++kk) {
      goffA[kk][j] = (aRow0 + row) * (long)lda + kk * 32 + kalt;
      goffB[kk][j] = (bRow0 + row) * (long)ldb + kk * 32 + kalt;
    }
  }
  int raddrA[8];
#pragma unroll
  for (int m = 0; m < 8; ++m) {
    const int row = wm * 128 + m * 16 + l15;
    raddrA[m] = row * 64 + ((lhi ^ ((row >> 1) & 3)) << 4);
  }
  int raddrB[4];
#pragma unroll
  for (int n = 0; n < 4; ++n) {
    const int row = wn * 64 + n * 16 + l15;
    raddrB[n] = row * 64 + ((lhi ^ ((row >> 1) & 3)) << 4);
  }

  const f32x4 z4 = {0.f, 0.f, 0.f, 0.f};
#pragma unroll
  for (int m = 0; m < 8; ++m)
#pragma unroll
    for (int n = 0; n < 4; ++n) acc[m][n] = z4;

  auto stageA = [&](int s, int kk, int T) {
    char* dst = lds + s * SLOT + kk * SLICE;
    const long k0 = (long)T << 6;
#pragma unroll
    for (int j = 0; j < 2; ++j) gload16(A + goffA[kk][j] + k0, dst + ldsoff[j]);
  };
  auto stageB = [&](int s, int kk, int T) {
    char* dst = lds + s * SLOT + A_BYTES + kk * SLICE;
    const long k0 = (long)T << 6;
#pragma unroll
    for (int j = 0; j < 2; ++j) gload16(Bt + goffB[kk][j] + k0, dst + ldsoff[j]);
  };

  stageA(0, 0, 0); stageB(0, 0, 0);
  stageA(0, 1, 0); stageB(0, 1, 0);
  wait_vm<4>();
  __builtin_amdgcn_s_barrier();

  int cur = 0;
  for (int t = 0; t < nt64; ++t) {
    const char* sb = lds + cur * SLOT;
    const int nxt = cur ^ 1;
    const bool pf = (t + 1 < nt64);
    bf16x8 a0[4], a1[4], b0[4], b1[4];
    // ---- P1: read B(kk0)+A(m0..3,kk0); stage A-slice0(t+1)
#pragma unroll
    for (int n = 0; n < 4; ++n) b0[n] = *(const bf16x8*)(sb + A_BYTES + raddrB[n]);
#pragma unroll
    for (int m = 0; m < 4; ++m) a0[m] = *(const bf16x8*)(sb + raddrA[m]);
    if (pf) stageA(nxt, 0, t + 1);
    __builtin_amdgcn_s_barrier();
    __builtin_amdgcn_s_setprio(1);
#pragma unroll
    for (int m = 0; m < 4; ++m)
#pragma unroll
      for (int n = 0; n < 4; ++n) acc[m][n] = mfma16(a0[m], b0[n], acc[m][n]);
    __builtin_amdgcn_s_setprio(0);
    __builtin_amdgcn_s_barrier();
    // ---- P2: read A(m4..7,kk0); stage B-slice0(t+1); counted vmcnt
#pragma unroll
    for (int m = 0; m < 4; ++m) a1[m] = *(const bf16x8*)(sb + raddrA[4 + m]);
    if (pf) { stageB(nxt, 0, t + 1); wait_vm<4>(); }
    else wait_vm<0>();
    __builtin_amdgcn_s_barrier();
    __builtin_amdgcn_s_setprio(1);
#pragma unroll
    for (int m = 0; m < 4; ++m)
#pragma unroll
      for (int n = 0; n < 4; ++n)
        acc[4 + m][n] = mfma16(a1[m], b0[n], acc[4 + m][n]);
    __builtin_amdgcn_s_setprio(0);
    __builtin_amdgcn_s_barrier();
    // ---- P3: read B(kk1)+A(m0..3,kk1); stage A-slice1(t+1)
#pragma unroll
    for (int n = 0; n < 4; ++n)
      b1[n] = *(const bf16x8*)(sb + A_BYTES + SLICE + raddrB[n]);
#pragma unroll
    for (int m = 0; m < 4; ++m) a0[m] = *(const bf16x8*)(sb + SLICE + raddrA[m]);
    if (pf) stageA(nxt, 1, t + 1);
    __builtin_amdgcn_s_barrier();
    __builtin_amdgcn_s_setprio(1);
#pragma unroll
    for (int m = 0; m < 4; ++m)
#pragma unroll
      for (int n = 0; n < 4; ++n) acc[m][n] = mfma16(a0[m], b1[n], acc[m][n]);
    __builtin_amdgcn_s_setprio(0);
    __builtin_amdgcn_s_barrier();
    // ---- P4: read A(m4..7,kk1); stage B-slice1(t+1); counted vmcnt
#pragma unroll
    for (int m = 0; m < 4; ++m)
      a1[m] = *(const bf16x8*)(sb + SLICE + raddrA[4 + m]);
    if (pf) { stageB(nxt, 1, t + 1); wait_vm<4>(); }
    __builtin_amdgcn_s_barrier();
    __builtin_amdgcn_s_setprio(1);
#pragma unroll
    for (int m = 0; m < 4; ++m)
#pragma unroll
      for (int n = 0; n < 4; ++n)
        acc[4 + m][n] = mfma16(a1[m], b1[n], acc[4 + m][n]);
    __builtin_amdgcn_s_setprio(0);
    __builtin_amdgcn_s_barrier();
    cur = nxt;
  }
}

// ---- fused QKV: X[8192,1024] x {Wq,Wk,Wv}^T. BM256xBN128, grid 768. ----
__global__ __launch_bounds__(256, 2) void qkv_kernel(
    const unsigned short* __restrict__ X, const unsigned short* __restrict__ TQ,
    const unsigned short* __restrict__ TK, const unsigned short* __restrict__ TV,
    const float* __restrict__ bq, const float* __restrict__ bk,
    const float* __restrict__ bv, unsigned short* __restrict__ Q16,
    unsigned short* __restrict__ K16, unsigned short* __restrict__ VT) {
  __shared__ char lds[3 * 24576];
  const int wgid = swz8(blockIdx.x, 96);
  const int tm = wgid / 24, tn = wgid % 24;
  const int w = tn >> 3, c = tn & 7;
  const unsigned short* Bt = w == 0 ? TQ : (w == 1 ? TK : TV);
  const float* bias = w == 0 ? bq : (w == 1 ? bk : bv);

  f32x4 acc[8][4];
  gemm_core(X, Bt, 1024, 1024, 32, (long)tm * 256, (long)c * 128, lds, acc);

  const int tid = threadIdx.x, lane = tid & 63, wid = tid >> 6;
  const int wm = wid >> 1, wn = wid & 1;
  const int l15 = lane & 15, lhi = lane >> 4;
  const int rowBase = tm * 256 + wm * 128;
  const int colBase = c * 128 + wn * 64;  // within-weight column (D index)
  if (w < 2) {
    unsigned short* C = w == 0 ? Q16 : K16;
#pragma unroll
    for (int m = 0; m < 8; ++m)
#pragma unroll
      for (int n = 0; n < 4; ++n) {
        const int col = colBase + n * 16 + l15;
        const float bvv = bias[col];
#pragma unroll
        for (int j = 0; j < 4; ++j) {
          const int row = rowBase + m * 16 + lhi * 4 + j;
          C[(long)row * 1024 + col] = f2bf(acc[m][n][j] + bvv);
        }
      }
  } else {
#pragma unroll
    for (int m = 0; m < 8; ++m)
#pragma unroll
      for (int n = 0; n < 4; ++n) {
        const int col = colBase + n * 16 + l15;
        const float bvv = bias[col];
        const int row0 = rowBase + m * 16 + lhi * 4;
        const int b = row0 >> 11, s = row0 & 2047;
        u16x4 v;
#pragma unroll
        for (int j = 0; j < 4; ++j) v[j] = f2bf(acc[m][n][j] + bvv);
        *reinterpret_cast<u16x4*>(&VT[(long)b * 2097152 + (long)col * 2048 + s]) = v;
      }
  }
}

// ---- scores = Q K^T / 32 per batch, fp16 out. BM256xBN256 BK64, grid 256.
__global__ __launch_bounds__(512, 1) void scores_kernel(
    const unsigned short* __restrict__ Q16, const unsigned short* __restrict__ K16,
    unsigned short* __restrict__ SC16) {
  extern __shared__ char lds[];  // 131072 bytes
  const int wgid = swz8(blockIdx.x, 32);
  const int bz = wgid >> 6, tm = (wgid >> 3) & 7, tn = wgid & 7;
  const unsigned short* A = Q16 + (long)bz * 2097152;
  const unsigned short* Bt = K16 + (long)bz * 2097152;

  f32x4 acc[8][4];
  gemm_core3(A, Bt, 1024, 1024, 16, (long)tm * 256, (long)tn * 256, lds, acc);

  unsigned short* C = SC16 + (long)bz * 4194304;
  const int tid = threadIdx.x, lane = tid & 63, wid = tid >> 6;
  const int wm = wid >> 2, wn = wid & 3;
  const int l15 = lane & 15, lhi = lane >> 4;
  const int rowBase = tm * 256 + wm * 128;
  const int colBase = tn * 256 + wn * 64;
#pragma unroll
  for (int m = 0; m < 8; ++m)
#pragma unroll
    for (int n = 0; n < 4; ++n) {
      const int col = colBase + n * 16 + l15;
#pragma unroll
      for (int j = 0; j < 4; ++j) {
        const int row = rowBase + m * 16 + lhi * 4 + j;
        C[(long)row * 2048 + col] = f2h(acc[m][n][j] * (1.f / 32.f));
      }
    }
}

// ---- out = P V per batch (Bt = VT[D][S]). BM256xBN128, grid 256. ----
__global__ __launch_bounds__(256, 2) void pv_kernel(
    const unsigned short* __restrict__ P16, const unsigned short* __restrict__ VT,
    float* __restrict__ out) {
  __shared__ char lds[3 * 24576];
  const int wgid = swz8(blockIdx.x, 32);
  const int bz = wgid >> 6, tm = (wgid >> 3) & 7, tn = wgid & 7;
  const unsigned short* A = P16 + (long)bz * 4194304;
  const unsigned short* Bt = VT + (long)bz * 2097152;

  f32x4 acc[8][4];
  gemm_core(A, Bt, 2048, 2048, 64, (long)tm * 256, (long)tn * 128, lds, acc);

  float* C = out + (long)bz * 2097152;
  const int tid = threadIdx.x, lane = tid & 63, wid = tid >> 6;
  const int wm = wid >> 1, wn = wid & 1;
  const int l15 = lane & 15, lhi = lane >> 4;
  const int rowBase = tm * 256 + wm * 128;
  const int colBase = tn * 128 + wn * 64;
#pragma unroll
  for (int m = 0; m < 8; ++m)
#pragma unroll
    for (int n = 0; n < 4; ++n) {
      const int col = colBase + n * 16 + l15;
#pragma unroll
      for (int j = 0; j < 4; ++j) {
        const int row = rowBase + m * 16 + lhi * 4 + j;
        C[(long)row * 1024 + col] = acc[m][n][j];
      }
    }
}

// ---- merged cvt: X fp32->bf16 (blocks [0,8192)) and W->W^T bf16
//      (blocks [8192,11264): 3 weights x 1024 blocks, 4 elems/thread).
__global__ __launch_bounds__(256) void cvt_all(
    const float* __restrict__ x, unsigned short* __restrict__ X16,
    const float* __restrict__ w0, const float* __restrict__ w1,
    const float* __restrict__ w2, unsigned short* __restrict__ t0,
    unsigned short* __restrict__ t1, unsigned short* __restrict__ t2) {
  const int bid = blockIdx.x;
  const int tid = threadIdx.x;
  if (bid < 8192) {
    int i = bid * 256 + tid;
    float4 v = reinterpret_cast<const float4*>(x)[i];
    u16x4 r;
    r[0] = f2bf(v.x); r[1] = f2bf(v.y); r[2] = f2bf(v.z); r[3] = f2bf(v.w);
    reinterpret_cast<u16x4*>(X16)[i] = r;
  } else {
    const int b2 = bid - 8192;
    const int wsel = b2 >> 10, blk = b2 & 1023;
    const float* w = wsel == 0 ? w0 : (wsel == 1 ? w1 : w2);
    unsigned short* t = wsel == 0 ? t0 : (wsel == 1 ? t1 : t2);
    const int base = blk * 1024;
#pragma unroll
    for (int e = 0; e < 4; ++e) {
      const int id = base + e * 256 + tid;
      const int k = id >> 10, n = id & 1023;
      t[n * 1024 + k] = f2bf(w[id]);
    }
  }
}

// ---- row softmax: fp16 scores -> bf16 P.  One block per row (8 elems/thr).
__global__ __launch_bounds__(256) void softmax_rows(const unsigned short* __restrict__ S,
                                                    unsigned short* __restrict__ P) {
  const long row = blockIdx.x;
  const u16x8* src = reinterpret_cast<const u16x8*>(S + row * 2048);
  const int tid = threadIdx.x;
  u16x8 a = src[tid];
  float v[8];
#pragma unroll
  for (int i = 0; i < 8; ++i) v[i] = h2f(a[i]);
  float m = v[0];
#pragma unroll
  for (int i = 1; i < 8; ++i) m = fmaxf(m, v[i]);
#pragma unroll
  for (int o = 32; o > 0; o >>= 1) m = fmaxf(m, __shfl_xor(m, o));
  __shared__ float red[8];
  const int wid = tid >> 6, lane = tid & 63;
  if (lane == 0) red[wid] = m;
  __syncthreads();
  m = fmaxf(fmaxf(red[0], red[1]), fmaxf(red[2], red[3]));
  float s = 0.f;
#pragma unroll
  for (int i = 0; i < 8; ++i) { v[i] = __expf(v[i] - m); s += v[i]; }
#pragma unroll
  for (int o = 32; o > 0; o >>= 1) s += __shfl_xor(s, o);
  if (lane == 0) red[4 + wid] = s;
  __syncthreads();
  s = (red[4] + red[5]) + (red[6] + red[7]);
  const float inv = 1.f / s;
  u16x8 p;
#pragma unroll
  for (int i = 0; i < 8; ++i) p[i] = f2bf(v[i] * inv);
  reinterpret_cast<u16x8*>(P + row * 2048)[tid] = p;
}

extern "C" void kernel_launch(void* const* d_in, const int* in_sizes, int n_in,
                              void* d_out, int out_size, void* d_ws, size_t ws_size,
                              hipStream_t stream) {
  const float* x  = (const float*)d_in[0];
  const float* Wq = (const float*)d_in[1];
  const float* bq = (const float*)d_in[2];
  const float* Wk = (const float*)d_in[3];
  const float* bk = (const float*)d_in[4];
  const float* Wv = (const float*)d_in[5];
  const float* bv = (const float*)d_in[6];
  float* out = (float*)d_out;

  char* ws = (char*)d_ws;
  const size_t MB = 1024 * 1024;
  unsigned short* X16 = (unsigned short*)(ws);
  unsigned short* TQ  = (unsigned short*)(ws + 16 * MB);
  unsigned short* TK  = (unsigned short*)(ws + 18 * MB);
  unsigned short* TV  = (unsigned short*)(ws + 20 * MB);
  unsigned short* Q16 = (unsigned short*)(ws + 22 * MB);
  unsigned short* K16 = (unsigned short*)(ws + 38 * MB);
  unsigned short* VT  = (unsigned short*)(ws + 54 * MB);
  unsigned short* SC16 = (unsigned short*)(ws + 70 * MB);
  unsigned short* P16 = Q16;  // alias Q16+K16 (32MB), dead after scores GEMM

  // allow 128KB dynamic LDS for scores_kernel (host-side attr, not captured)
  static bool attr_set = false;
  if (!attr_set) {
    hipFuncSetAttribute(reinterpret_cast<const void*>(scores_kernel),
                        hipFuncAttributeMaxDynamicSharedMemorySize, 131072);
    attr_set = true;
  }

  cvt_all<<<11264, 256, 0, stream>>>(x, X16, Wq, Wk, Wv, TQ, TK, TV);

  qkv_kernel<<<768, 256, 0, stream>>>(X16, TQ, TK, TV, bq, bk, bv, Q16, K16, VT);
  scores_kernel<<<256, 512, 131072, stream>>>(Q16, K16, SC16);
  softmax_rows<<<4 * 2048, 256, 0, stream>>>(SC16, P16);
  pv_kernel<<<256, 256, 0, stream>>>(P16, VT, out);

  (void)in_sizes; (void)n_in; (void)out_size; (void)ws_size;
}

// Round 7
// 174.535 us; speedup vs baseline: 1.0490x; 1.0432x over previous
//
#include <hip/hip_runtime.h>
#include <stdint.h>

// B=4, S=2048, D=1024 self-attention, fp32 in/out.
// cvt(fp32->bf16, W^T) -> fused QKV GEMM -> scores GEMM (fp16 out, *1/32) ->
// softmax (fp16 in -> bf16 P) -> PV GEMM (fp32 out).
//
// r16: exact revert to r11, the session best (174.3us). Final ledger:
// r10 -11 (2-phase graft), r11 BEST, r12 -17 (128^2 tiles: FETCH 2x,
// 16 MFMA/barrier), r13 -6 (512-thr lockstep pv), r14 -9 (BN=64 pv),
// r15 -8 (cvt_all merge: tail-imbalanced grid -- isolated regression).
// Rules extracted: (1) >=32 MFMA per wave per barrier-pair; (2) overlap
// must come from independent blocks, not lockstep waves; (3) uniform
// launches beat merged imbalanced ones; (4) every bundled micro-opt must
// be isolated first.
//   qkv:    256-thr BM256xBN128 r6-core, grid 768, 2 blk/CU   (~832 TF)
//   scores: 512-thr BM=BN=256 BK64 4-phase dbuf, grid 256     (~840 TF)
//   pv:     256-thr BM256xBN128 r6-core, grid 256, 1 blk/CU   (~782 TF)
// Workspace: [0,16M) X16 | [16,22M) TQ/TK/TV | [22,38M) Q16 | [38,54M) K16 |
//            [54,70M) VT [B][D][S] | [70,102M) SC16 fp16 | P16 aliases Q16+K16.

typedef __attribute__((ext_vector_type(8))) short bf16x8;
typedef __attribute__((ext_vector_type(4))) float f32x4;
typedef __attribute__((ext_vector_type(4))) unsigned short u16x4;
typedef __attribute__((ext_vector_type(8))) unsigned short u16x8;

__device__ __forceinline__ unsigned short f2bf(float f) {
  union { float f; unsigned u; } v; v.f = f;
  return (unsigned short)((v.u + 0x7FFFu + ((v.u >> 16) & 1u)) >> 16);
}
__device__ __forceinline__ unsigned short f2h(float f) {
  union { _Float16 h; unsigned short u; } v; v.h = (_Float16)f;
  return v.u;
}
__device__ __forceinline__ float h2f(unsigned short u) {
  union { unsigned short u; _Float16 h; } v; v.u = u;
  return (float)v.h;
}

__device__ __forceinline__ void gload16(const void* g, void* l) {
  __builtin_amdgcn_global_load_lds(
      (const __attribute__((address_space(1))) unsigned int*)g,
      (__attribute__((address_space(3))) unsigned int*)l, 16, 0, 0);
}

template <int N>
__device__ __forceinline__ void wait_vm() {
  asm volatile("s_waitcnt vmcnt(%0)" ::"n"(N) : "memory");
}

__device__ __forceinline__ int swz8(int bid, int cpx) {
  return (bid & 7) * cpx + (bid >> 3);  // bijective when nwg%8==0
}

__device__ __forceinline__ f32x4 mfma16(bf16x8 a, bf16x8 b, f32x4 c) {
  return __builtin_amdgcn_mfma_f32_16x16x32_bf16(a, b, c, 0, 0, 0);
}

// ================= r6-proven core: 256 thr, BM256 x BN128, ring-3 ==========
__device__ __forceinline__ void gemm_core(
    const unsigned short* __restrict__ A, const unsigned short* __restrict__ Bt,
    const int lda, const int ldb, const int nt,
    const long aRow0, const long bRow0, char* lds,
    f32x4 (&acc)[8][4]) {
  constexpr int A_BYTES = 256 * 64;           // 16KB
  constexpr int SLOT = A_BYTES + 128 * 64;    // 24KB
  constexpr int LA = 4, LB = 2, L = LA + LB;  // 16B gloads per thread per tile
  const int tid = threadIdx.x;
  const int lane = tid & 63;
  const int wid = tid >> 6;
  const int wm = wid >> 1, wn = wid & 1;
  const int l15 = lane & 15, lhi = lane >> 4;

  long goffA[LA]; int ldsoffA[LA];
#pragma unroll
  for (int j = 0; j < LA; ++j) {
    const int local = j * 4096 + tid * 16;
    const int row = local >> 6, ch = (local >> 4) & 3;
    goffA[j] = (aRow0 + row) * (long)lda + ((ch ^ ((row >> 1) & 3)) << 3);
    ldsoffA[j] = local;
  }
  long goffB[LB]; int ldsoffB[LB];
#pragma unroll
  for (int j = 0; j < LB; ++j) {
    const int local = j * 4096 + tid * 16;
    const int row = local >> 6, ch = (local >> 4) & 3;
    goffB[j] = (bRow0 + row) * (long)ldb + ((ch ^ ((row >> 1) & 3)) << 3);
    ldsoffB[j] = A_BYTES + local;
  }
  int raddrA[8];
#pragma unroll
  for (int m = 0; m < 8; ++m) {
    const int row = wm * 128 + m * 16 + l15;
    raddrA[m] = row * 64 + ((lhi ^ ((row >> 1) & 3)) << 4);
  }
  int raddrB[4];
#pragma unroll
  for (int n = 0; n < 4; ++n) {
    const int row = wn * 64 + n * 16 + l15;
    raddrB[n] = A_BYTES + row * 64 + ((lhi ^ ((row >> 1) & 3)) << 4);
  }

  const f32x4 z4 = {0.f, 0.f, 0.f, 0.f};
#pragma unroll
  for (int m = 0; m < 8; ++m)
#pragma unroll
    for (int n = 0; n < 4; ++n) acc[m][n] = z4;

  auto stage_tile = [&](int T) {
    char* dst = lds + (T % 3) * SLOT;
    const int k0 = T << 5;
#pragma unroll
    for (int j = 0; j < LA; ++j) gload16(A + goffA[j] + k0, dst + ldsoffA[j]);
#pragma unroll
    for (int j = 0; j < LB; ++j) gload16(Bt + goffB[j] + k0, dst + ldsoffB[j]);
  };

  stage_tile(0);
  stage_tile(1);
  wait_vm<L>();
  __builtin_amdgcn_s_barrier();

  for (int t = 0; t < nt; ++t) {
    const char* sb = lds + (t % 3) * SLOT;
    bf16x8 af[8], bfr[4];
#pragma unroll
    for (int n = 0; n < 4; ++n) bfr[n] = *(const bf16x8*)(sb + raddrB[n]);
#pragma unroll
    for (int m = 0; m < 8; ++m) af[m] = *(const bf16x8*)(sb + raddrA[m]);
    if (t + 2 < nt) stage_tile(t + 2);
    __builtin_amdgcn_s_setprio(1);
#pragma unroll
    for (int m = 0; m < 8; ++m)
#pragma unroll
      for (int n = 0; n < 4; ++n) acc[m][n] = mfma16(af[m], bfr[n], acc[m][n]);
    __builtin_amdgcn_s_setprio(0);
    if (t + 2 < nt) wait_vm<L>();
    else if (t + 1 < nt) wait_vm<0>();
    __builtin_amdgcn_s_barrier();
  }
}

// ====== r11 scores core: 512 thr, BM=BN=256, BK=64, double-buffer ==========
// 4 phases x 16 MFMA per K-tile; counted vmcnt(4) twice per tile (never 0
// mid-loop).  Wait algebra: end P2 outstanding {A1,B1(t),A0,B0(t+1)}=8 ->
// vmcnt(4) retires A1,B1(t) for P3/P4; end P4 outstanding {t+1's 8} ->
// vmcnt(4) retires A0,B0(t+1) for next-iter P1/P2.
__device__ __forceinline__ void gemm_core3(
    const unsigned short* __restrict__ A, const unsigned short* __restrict__ Bt,
    const int lda, const int ldb, const int nt64,
    const long aRow0, const long bRow0, char* lds,
    f32x4 (&acc)[8][4]) {
  constexpr int SLICE = 256 * 64;     // 16KB
  constexpr int A_BYTES = 2 * SLICE;  // 32KB
  constexpr int SLOT = 2 * A_BYTES;   // 64KB
  const int tid = threadIdx.x;
  const int lane = tid & 63;
  const int wid = tid >> 6;
  const int wm = wid >> 2, wn = wid & 3;
  const int l15 = lane & 15, lhi = lane >> 4;

  long goffA[2][2], goffB[2][2];  // [kk][j]
  int ldsoff[2];
#pragma unroll
  for (int j = 0; j < 2; ++j) {
    const int local = j * 8192 + tid * 16;
    const int row = local >> 6, ch = (local >> 4) & 3;
    ldsoff[j] = local;
    const int kalt = (ch ^ ((row >> 1) & 3)) << 3;
#pragma unroll
    for (int kk = 0; kk < 2; ++kk) {
      goffA[kk][j] = (aRow0 + row) * (long)lda + kk * 32 + kalt;
      goffB[kk][j] = (bRow0 + row) * (long)ldb + kk * 32 + kalt;
    }
  }
  int raddrA[8];
#pragma unroll
  for (int m = 0; m < 8; ++m) {
    const int row = wm * 128 + m * 16 + l15;
    raddrA[m] = row * 64 + ((lhi ^ ((row >> 1) & 3)) << 4);
  }
  int raddrB[4];
#pragma unroll
  for (int n = 0; n < 4; ++n) {
    const int row = wn * 64 + n * 16 + l15;
    raddrB[n] = row * 64 + ((lhi ^ ((row >> 1) & 3)) << 4);
  }

  const f32x4 z4 = {0.f, 0.f, 0.f, 0.f};
#pragma unroll
  for (int m = 0; m < 8; ++m)
#pragma unroll
    for (int n = 0; n < 4; ++n) acc[m][n] = z4;

  auto stageA = [&](int s, int kk, int T) {
    char* dst = lds + s * SLOT + kk * SLICE;
    const long k0 = (long)T << 6;
#pragma unroll
    for (int j = 0; j < 2; ++j) gload16(A + goffA[kk][j] + k0, dst + ldsoff[j]);
  };
  auto stageB = [&](int s, int kk, int T) {
    char* dst = lds + s * SLOT + A_BYTES + kk * SLICE;
    const long k0 = (long)T << 6;
#pragma unroll
    for (int j = 0; j < 2; ++j) gload16(Bt + goffB[kk][j] + k0, dst + ldsoff[j]);
  };

  stageA(0, 0, 0); stageB(0, 0, 0);
  stageA(0, 1, 0); stageB(0, 1, 0);
  wait_vm<4>();
  __builtin_amdgcn_s_barrier();

  int cur = 0;
  for (int t = 0; t < nt64; ++t) {
    const char* sb = lds + cur * SLOT;
    const int nxt = cur ^ 1;
    const bool pf = (t + 1 < nt64);
    bf16x8 a0[4], a1[4], b0[4], b1[4];
    // ---- P1: read B(kk0)+A(m0..3,kk0); stage A-slice0(t+1)
#pragma unroll
    for (int n = 0; n < 4; ++n) b0[n] = *(const bf16x8*)(sb + A_BYTES + raddrB[n]);
#pragma unroll
    for (int m = 0; m < 4; ++m) a0[m] = *(const bf16x8*)(sb + raddrA[m]);
    if (pf) stageA(nxt, 0, t + 1);
    __builtin_amdgcn_s_barrier();
    __builtin_amdgcn_s_setprio(1);
#pragma unroll
    for (int m = 0; m < 4; ++m)
#pragma unroll
      for (int n = 0; n < 4; ++n) acc[m][n] = mfma16(a0[m], b0[n], acc[m][n]);
    __builtin_amdgcn_s_setprio(0);
    __builtin_amdgcn_s_barrier();
    // ---- P2: read A(m4..7,kk0); stage B-slice0(t+1); counted vmcnt
#pragma unroll
    for (int m = 0; m < 4; ++m) a1[m] = *(const bf16x8*)(sb + raddrA[4 + m]);
    if (pf) { stageB(nxt, 0, t + 1); wait_vm<4>(); }
    else wait_vm<0>();
    __builtin_amdgcn_s_barrier();
    __builtin_amdgcn_s_setprio(1);
#pragma unroll
    for (int m = 0; m < 4; ++m)
#pragma unroll
      for (int n = 0; n < 4; ++n)
        acc[4 + m][n] = mfma16(a1[m], b0[n], acc[4 + m][n]);
    __builtin_amdgcn_s_setprio(0);
    __builtin_amdgcn_s_barrier();
    // ---- P3: read B(kk1)+A(m0..3,kk1); stage A-slice1(t+1)
#pragma unroll
    for (int n = 0; n < 4; ++n)
      b1[n] = *(const bf16x8*)(sb + A_BYTES + SLICE + raddrB[n]);
#pragma unroll
    for (int m = 0; m < 4; ++m) a0[m] = *(const bf16x8*)(sb + SLICE + raddrA[m]);
    if (pf) stageA(nxt, 1, t + 1);
    __builtin_amdgcn_s_barrier();
    __builtin_amdgcn_s_setprio(1);
#pragma unroll
    for (int m = 0; m < 4; ++m)
#pragma unroll
      for (int n = 0; n < 4; ++n) acc[m][n] = mfma16(a0[m], b1[n], acc[m][n]);
    __builtin_amdgcn_s_setprio(0);
    __builtin_amdgcn_s_barrier();
    // ---- P4: read A(m4..7,kk1); stage B-slice1(t+1); counted vmcnt
#pragma unroll
    for (int m = 0; m < 4; ++m)
      a1[m] = *(const bf16x8*)(sb + SLICE + raddrA[4 + m]);
    if (pf) { stageB(nxt, 1, t + 1); wait_vm<4>(); }
    __builtin_amdgcn_s_barrier();
    __builtin_amdgcn_s_setprio(1);
#pragma unroll
    for (int m = 0; m < 4; ++m)
#pragma unroll
      for (int n = 0; n < 4; ++n)
        acc[4 + m][n] = mfma16(a1[m], b1[n], acc[4 + m][n]);
    __builtin_amdgcn_s_setprio(0);
    __builtin_amdgcn_s_barrier();
    cur = nxt;
  }
}

// ---- fused QKV: X[8192,1024] x {Wq,Wk,Wv}^T. BM256xBN128, grid 768. ----
__global__ __launch_bounds__(256, 2) void qkv_kernel(
    const unsigned short* __restrict__ X, const unsigned short* __restrict__ TQ,
    const unsigned short* __restrict__ TK, const unsigned short* __restrict__ TV,
    const float* __restrict__ bq, const float* __restrict__ bk,
    const float* __restrict__ bv, unsigned short* __restrict__ Q16,
    unsigned short* __restrict__ K16, unsigned short* __restrict__ VT) {
  __shared__ char lds[3 * 24576];
  const int wgid = swz8(blockIdx.x, 96);
  const int tm = wgid / 24, tn = wgid % 24;
  const int w = tn >> 3, c = tn & 7;
  const unsigned short* Bt = w == 0 ? TQ : (w == 1 ? TK : TV);
  const float* bias = w == 0 ? bq : (w == 1 ? bk : bv);

  f32x4 acc[8][4];
  gemm_core(X, Bt, 1024, 1024, 32, (long)tm * 256, (long)c * 128, lds, acc);

  const int tid = threadIdx.x, lane = tid & 63, wid = tid >> 6;
  const int wm = wid >> 1, wn = wid & 1;
  const int l15 = lane & 15, lhi = lane >> 4;
  const int rowBase = tm * 256 + wm * 128;
  const int colBase = c * 128 + wn * 64;  // within-weight column (D index)
  if (w < 2) {
    unsigned short* C = w == 0 ? Q16 : K16;
#pragma unroll
    for (int m = 0; m < 8; ++m)
#pragma unroll
      for (int n = 0; n < 4; ++n) {
        const int col = colBase + n * 16 + l15;
        const float bvv = bias[col];
#pragma unroll
        for (int j = 0; j < 4; ++j) {
          const int row = rowBase + m * 16 + lhi * 4 + j;
          C[(long)row * 1024 + col] = f2bf(acc[m][n][j] + bvv);
        }
      }
  } else {
#pragma unroll
    for (int m = 0; m < 8; ++m)
#pragma unroll
      for (int n = 0; n < 4; ++n) {
        const int col = colBase + n * 16 + l15;
        const float bvv = bias[col];
        const int row0 = rowBase + m * 16 + lhi * 4;
        const int b = row0 >> 11, s = row0 & 2047;
        u16x4 v;
#pragma unroll
        for (int j = 0; j < 4; ++j) v[j] = f2bf(acc[m][n][j] + bvv);
        *reinterpret_cast<u16x4*>(&VT[(long)b * 2097152 + (long)col * 2048 + s]) = v;
      }
  }
}

// ---- scores = Q K^T / 32 per batch, fp16 out. BM256xBN256 BK64, grid 256.
__global__ __launch_bounds__(512, 1) void scores_kernel(
    const unsigned short* __restrict__ Q16, const unsigned short* __restrict__ K16,
    unsigned short* __restrict__ SC16) {
  extern __shared__ char lds[];  // 131072 bytes
  const int wgid = swz8(blockIdx.x, 32);
  const int bz = wgid >> 6, tm = (wgid >> 3) & 7, tn = wgid & 7;
  const unsigned short* A = Q16 + (long)bz * 2097152;
  const unsigned short* Bt = K16 + (long)bz * 2097152;

  f32x4 acc[8][4];
  gemm_core3(A, Bt, 1024, 1024, 16, (long)tm * 256, (long)tn * 256, lds, acc);

  unsigned short* C = SC16 + (long)bz * 4194304;
  const int tid = threadIdx.x, lane = tid & 63, wid = tid >> 6;
  const int wm = wid >> 2, wn = wid & 3;
  const int l15 = lane & 15, lhi = lane >> 4;
  const int rowBase = tm * 256 + wm * 128;
  const int colBase = tn * 256 + wn * 64;
#pragma unroll
  for (int m = 0; m < 8; ++m)
#pragma unroll
    for (int n = 0; n < 4; ++n) {
      const int col = colBase + n * 16 + l15;
#pragma unroll
      for (int j = 0; j < 4; ++j) {
        const int row = rowBase + m * 16 + lhi * 4 + j;
        C[(long)row * 2048 + col] = f2h(acc[m][n][j] * (1.f / 32.f));
      }
    }
}

// ---- out = P V per batch (Bt = VT[D][S]). BM256xBN128, grid 256. ----
__global__ __launch_bounds__(256, 2) void pv_kernel(
    const unsigned short* __restrict__ P16, const unsigned short* __restrict__ VT,
    float* __restrict__ out) {
  __shared__ char lds[3 * 24576];
  const int wgid = swz8(blockIdx.x, 32);
  const int bz = wgid >> 6, tm = (wgid >> 3) & 7, tn = wgid & 7;
  const unsigned short* A = P16 + (long)bz * 4194304;
  const unsigned short* Bt = VT + (long)bz * 2097152;

  f32x4 acc[8][4];
  gemm_core(A, Bt, 2048, 2048, 64, (long)tm * 256, (long)tn * 128, lds, acc);

  float* C = out + (long)bz * 2097152;
  const int tid = threadIdx.x, lane = tid & 63, wid = tid >> 6;
  const int wm = wid >> 1, wn = wid & 1;
  const int l15 = lane & 15, lhi = lane >> 4;
  const int rowBase = tm * 256 + wm * 128;
  const int colBase = tn * 128 + wn * 64;
#pragma unroll
  for (int m = 0; m < 8; ++m)
#pragma unroll
    for (int n = 0; n < 4; ++n) {
      const int col = colBase + n * 16 + l15;
#pragma unroll
      for (int j = 0; j < 4; ++j) {
        const int row = rowBase + m * 16 + lhi * 4 + j;
        C[(long)row * 1024 + col] = acc[m][n][j];
      }
    }
}

// ---- fp32 -> bf16, 4 elems/thread ----
__global__ __launch_bounds__(256) void cvt4(const float* __restrict__ in,
                                            unsigned short* __restrict__ out) {
  int i = blockIdx.x * 256 + threadIdx.x;
  float4 v = reinterpret_cast<const float4*>(in)[i];
  u16x4 r;
  r[0] = f2bf(v.x); r[1] = f2bf(v.y); r[2] = f2bf(v.z); r[3] = f2bf(v.w);
  reinterpret_cast<u16x4*>(out)[i] = r;
}

// ---- W [K,N] fp32 -> Wt [N,K] bf16 ----
__global__ __launch_bounds__(256) void cvtWt(
    const float* __restrict__ w0, const float* __restrict__ w1, const float* __restrict__ w2,
    unsigned short* __restrict__ t0, unsigned short* __restrict__ t1, unsigned short* __restrict__ t2) {
  const float* w = blockIdx.y == 0 ? w0 : (blockIdx.y == 1 ? w1 : w2);
  unsigned short* t = blockIdx.y == 0 ? t0 : (blockIdx.y == 1 ? t1 : t2);
  int id = blockIdx.x * 256 + threadIdx.x;
  int k = id >> 10, n = id & 1023;
  t[n * 1024 + k] = f2bf(w[id]);
}

// ---- row softmax: fp16 scores -> bf16 P.  One block per row (8 elems/thr).
__global__ __launch_bounds__(256) void softmax_rows(const unsigned short* __restrict__ S,
                                                    unsigned short* __restrict__ P) {
  const long row = blockIdx.x;
  const u16x8* src = reinterpret_cast<const u16x8*>(S + row * 2048);
  const int tid = threadIdx.x;
  u16x8 a = src[tid];
  float v[8];
#pragma unroll
  for (int i = 0; i < 8; ++i) v[i] = h2f(a[i]);
  float m = v[0];
#pragma unroll
  for (int i = 1; i < 8; ++i) m = fmaxf(m, v[i]);
#pragma unroll
  for (int o = 32; o > 0; o >>= 1) m = fmaxf(m, __shfl_xor(m, o));
  __shared__ float red[8];
  const int wid = tid >> 6, lane = tid & 63;
  if (lane == 0) red[wid] = m;
  __syncthreads();
  m = fmaxf(fmaxf(red[0], red[1]), fmaxf(red[2], red[3]));
  float s = 0.f;
#pragma unroll
  for (int i = 0; i < 8; ++i) { v[i] = __expf(v[i] - m); s += v[i]; }
#pragma unroll
  for (int o = 32; o > 0; o >>= 1) s += __shfl_xor(s, o);
  if (lane == 0) red[4 + wid] = s;
  __syncthreads();
  s = (red[4] + red[5]) + (red[6] + red[7]);
  const float inv = 1.f / s;
  u16x8 p;
#pragma unroll
  for (int i = 0; i < 8; ++i) p[i] = f2bf(v[i] * inv);
  reinterpret_cast<u16x8*>(P + row * 2048)[tid] = p;
}

extern "C" void kernel_launch(void* const* d_in, const int* in_sizes, int n_in,
                              void* d_out, int out_size, void* d_ws, size_t ws_size,
                              hipStream_t stream) {
  const float* x  = (const float*)d_in[0];
  const float* Wq = (const float*)d_in[1];
  const float* bq = (const float*)d_in[2];
  const float* Wk = (const float*)d_in[3];
  const float* bk = (const float*)d_in[4];
  const float* Wv = (const float*)d_in[5];
  const float* bv = (const float*)d_in[6];
  float* out = (float*)d_out;

  char* ws = (char*)d_ws;
  const size_t MB = 1024 * 1024;
  unsigned short* X16 = (unsigned short*)(ws);
  unsigned short* TQ  = (unsigned short*)(ws + 16 * MB);
  unsigned short* TK  = (unsigned short*)(ws + 18 * MB);
  unsigned short* TV  = (unsigned short*)(ws + 20 * MB);
  unsigned short* Q16 = (unsigned short*)(ws + 22 * MB);
  unsigned short* K16 = (unsigned short*)(ws + 38 * MB);
  unsigned short* VT  = (unsigned short*)(ws + 54 * MB);
  unsigned short* SC16 = (unsigned short*)(ws + 70 * MB);
  unsigned short* P16 = Q16;  // alias Q16+K16 (32MB), dead after scores GEMM

  // allow 128KB dynamic LDS for scores_kernel (host-side attr, not captured)
  static bool attr_set = false;
  if (!attr_set) {
    hipFuncSetAttribute(reinterpret_cast<const void*>(scores_kernel),
                        hipFuncAttributeMaxDynamicSharedMemorySize, 131072);
    attr_set = true;
  }

  cvt4<<<8192, 256, 0, stream>>>(x, X16);
  cvtWt<<<dim3(4096, 3), 256, 0, stream>>>(Wq, Wk, Wv, TQ, TK, TV);

  qkv_kernel<<<768, 256, 0, stream>>>(X16, TQ, TK, TV, bq, bk, bv, Q16, K16, VT);
  scores_kernel<<<256, 512, 131072, stream>>>(Q16, K16, SC16);
  softmax_rows<<<4 * 2048, 256, 0, stream>>>(SC16, P16);
  pv_kernel<<<256, 256, 0, stream>>>(P16, VT, out);

  (void)in_sizes; (void)n_in; (void)out_size; (void)ws_size;
}